// Round 7
// baseline (423.623 us; speedup 1.0000x reference)
//
#include <hip/hip_runtime.h>

#define NN 100000
#define FIN 128
#define HD 32
#define EE 3200000
#define NBUK 391            // coarse buckets of 256 nodes
#define EPB 6144            // edges per binning chunk (LDS-sort fits in 64KB)
#define NBLK ((EE + EPB - 1) / EPB)   // 521
#define CAP 10240           // slab per bucket; mean load 8192, +23 sigma margin

typedef unsigned int uint;
typedef unsigned short ushort;
typedef float vfloat4 __attribute__((ext_vector_type(4)));   // clang vector: nontemporal-ok

__device__ __forceinline__ ushort f2bf(float f) {
    uint b = __float_as_uint(f);
    return (ushort)((b + 0x7FFFu + ((b >> 16) & 1u)) >> 16);
}

// values < 2^31 and non-negative: for int64, low dword suffices
__device__ __forceinline__ int load_idx32_c(const int* __restrict__ ei, long long pos, int is64) {
    return is64 ? ei[pos * 2] : ei[pos];     // cached: col is re-read in scatter phase
}
__device__ __forceinline__ int load_idx32_nt(const int* __restrict__ ei, long long pos, int is64) {
    return is64 ? __builtin_nontemporal_load(ei + pos * 2)
                : __builtin_nontemporal_load(ei + pos);
}

// ---------------- zero the global bucket cursors ----------------
__global__ void zero_gcur(int* __restrict__ gcur) {
    for (int i = threadIdx.x; i < 6400; i += 512) gcur[i] = 0;
}

// ---------------- sortC_fused: hist + global segment claim + LDS-sorted scatter ----
// Replaces passA + scan_bucket + scan_total + old sortC. Bucket b owns slab
// [b*CAP, b*CAP+count). Within-bucket segment order across chunks is
// non-deterministic (fetch-add), which is fine: within-NODE edge order was
// already non-deterministic (passB's LDS atomic race), only the fp sum order
// changes, within tolerance. rec = {row17 | bf15(wt)<<17, col32}
__global__ __launch_bounds__(512) void sortC_fused(const int* __restrict__ ei,
                                                   const float* __restrict__ wt,
                                                   int* __restrict__ gcur,
                                                   uint2* __restrict__ erec2) {
    __shared__ uint2 lrec[EPB];      // 49152 B
    __shared__ int hist[NBUK];
    __shared__ int lbase[NBUK];      // this chunk's base within bucket slab
    __shared__ int lcombo[NBUK];     // b*CAP + lbase[b] - lstart[b]
    __shared__ int lcur[NBUK];
    __shared__ int sis64;
    int tid = threadIdx.x, blk = blockIdx.x;
    for (int b = tid; b < NBUK; b += 512) hist[b] = 0;
    if (tid < 64) {   // inline dtype detect: hi dwords of first 256 slots all zero => int64
        uint v = 0;
#pragma unroll
        for (int r = 0; r < 4; r++) v |= ((const uint*)ei)[2 * (tid + 64 * r) + 1];
        unsigned long long nz = __ballot(v != 0u);
        if (tid == 0) sis64 = (nz == 0ULL) ? 1 : 0;
    }
    __syncthreads();
    int is64 = sis64;
    int e0 = blk * EPB, e1 = e0 + EPB; if (e1 > EE) e1 = EE;
    // phase 1: LDS histogram of this chunk's cols (cached loads: re-read below hits L2)
    for (int e = e0 + tid; e < e1; e += 512) {
        int col = load_idx32_c(ei, (long long)EE + e, is64);
        atomicAdd(&hist[col >> 8], 1);
    }
    __syncthreads();
    // phase 2: one global fetch-add per present bucket claims this chunk's segment
    for (int b = tid; b < NBUK; b += 512)
        lbase[b] = hist[b] ? atomicAdd(&gcur[b * 16], hist[b]) : 0;   // 64B-padded cursors
    __syncthreads();
    // phase 3: wave 0 exclusive scan of hist -> LDS bin starts + output combo
    if (tid < 64) {
        int run = 0;
        for (int c = 0; c < NBUK; c += 64) {
            int b = c + tid;
            int v = (b < NBUK) ? hist[b] : 0;
            int incl = v;
#pragma unroll
            for (int d = 1; d < 64; d <<= 1) {
                int t2 = __shfl_up(incl, d, 64);
                if (tid >= d) incl += t2;
            }
            if (b < NBUK) {
                int ls = run + incl - v;
                lcur[b] = ls;
                lcombo[b] = b * CAP + lbase[b] - ls;
            }
            run += __shfl(incl, 63, 64);
        }
    }
    __syncthreads();
    // phase 4: LDS binning (col re-read is L2-hot; row/wt first touch -> nontemporal)
    for (int e = e0 + tid; e < e1; e += 512) {
        int row = load_idx32_nt(ei, e, is64);
        int col = load_idx32_c(ei, (long long)EE + e, is64);
        uint nb = __float_as_uint(__builtin_nontemporal_load(wt + e));
        uint enc = ((nb + 0x8000u) >> 16) & 0x7FFFu;   // bf16 round, drop sign(=0)
        int pos = atomicAdd(&lcur[col >> 8], 1);       // LDS atomic
        uint2 r; r.x = (uint)row | (enc << 17); r.y = (uint)col;
        lrec[pos] = r;
    }
    __syncthreads();
    // phase 5: stream out, contiguous per bucket segment
    int m = e1 - e0;
    for (int slot = tid; slot < m; slot += 512) {
        uint2 r = lrec[slot];
        erec2[lcombo[r.y >> 8] + slot] = r;
    }
}

// ---------------- passB: per-bucket fine sort + degree/dinv (fused) ----------
__global__ __launch_bounds__(512) void passB_fine(const uint2* __restrict__ erec2,
                                                  const int* __restrict__ gcur,
                                                  uint* __restrict__ erecF,
                                                  int* __restrict__ estart, int* __restrict__ cnt,
                                                  float* __restrict__ dinv) {
    __shared__ int hist[256];
    __shared__ float wsum[256];
    __shared__ int off[256];
    __shared__ int cur[256];
    __shared__ int sd[256];
    int t = threadIdx.x, b = blockIdx.x;
    if (t < 256) { hist[t] = 0; wsum[t] = 0.f; }
    __syncthreads();
    int e0 = b * CAP, e1 = e0 + gcur[b * 16];
    for (int e = e0 + t; e < e1; e += 512) {
        uint2 r = erec2[e];
        int cl = (int)(r.y & 255u);
        atomicAdd(&hist[cl], 1);
        atomicAdd(&wsum[cl], __uint_as_float((r.x >> 17) << 16));
    }
    __syncthreads();
    int v = 0;
    if (t < 256) { v = hist[t]; sd[t] = v; }
    __syncthreads();
    for (int o = 1; o < 256; o <<= 1) {
        int x = (t >= o && t < 256) ? sd[t - o] : 0;
        __syncthreads();
        if (t < 256) sd[t] += x;
        __syncthreads();
    }
    if (t < 256) {
        off[t] = sd[t] - v;
        cur[t] = 0;
        int node = b * 256 + t;
        if (node < NN) {
            estart[node] = e0 + off[t];
            cnt[node] = v;
            dinv[node] = rsqrtf(1.0f + wsum[t]);   // 1 = self-loop weight
        }
    }
    __syncthreads();
    for (int e = e0 + t; e < e1; e += 512) {
        uint2 r = erec2[e];
        int cl = (int)(r.y & 255u);
        int p = atomicAdd(&cur[cl], 1);        // LDS atomic
        erecF[e0 + off[cl] + p] = r.x;         // dense per-node-sorted within slab
    }
}

// ---------------- xw = x @ [Wc_z | Wc_r | Wc_h]  (f32 VALU, bf16 output) -------
// Output layout per node: 32 features x 8B = 256B row.
// Feature j at byte 8j: { word0 = z_j | r_j<<16, word1 = h_j } (bf16 each).
// One aligned 8B load per lane per edge in agg_gate.
// dinv[row] folded here. xw16 ALIASES erec2 (dead after passB; same stream).
__global__ __launch_bounds__(256) void gemm_xw_kernel(
        const float* __restrict__ x,
        const float* __restrict__ Wz, const float* __restrict__ Wr, const float* __restrict__ Wh,
        const float* __restrict__ dinv,
        ushort* __restrict__ xw16) {
    __shared__ float Bs[128 * 96];   // Bs[k*96 + c], k GLOBAL (0..127)
    __shared__ float AsT[8 * 128];   // AsT[kk*128 + row], kk local (0..7)
    int tid = threadIdx.x;
    int tx = tid & 31, ty = tid >> 5;
    int rowBase = blockIdx.x * 128;

    for (int e = tid; e < 4096; e += 256) { int k = e >> 5, c = e & 31; Bs[k * 96 + c]      = Wz[e]; }
    for (int e = tid; e < 4096; e += 256) { int k = e >> 5, c = e & 31; Bs[k * 96 + 32 + c] = Wr[e]; }
    for (int e = tid; e < 4096; e += 256) { int k = e >> 5, c = e & 31; Bs[k * 96 + 64 + c] = Wh[e]; }

    float acc0[16], acc1[16], acc2[16];
#pragma unroll
    for (int r = 0; r < 16; r++) { acc0[r] = 0.f; acc1[r] = 0.f; acc2[r] = 0.f; }

    int lr = tid >> 1;
    int lc = (tid & 1) * 4;
    for (int k0 = 0; k0 < 128; k0 += 8) {
        __syncthreads();
        int gr = rowBase + lr;
        vfloat4 a4 = (vfloat4)(0.f);
        if (gr < NN) a4 = __builtin_nontemporal_load((const vfloat4*)(x + (long long)gr * FIN + k0 + lc));
        AsT[(lc + 0) * 128 + lr] = a4.x;
        AsT[(lc + 1) * 128 + lr] = a4.y;
        AsT[(lc + 2) * 128 + lr] = a4.z;
        AsT[(lc + 3) * 128 + lr] = a4.w;
        __syncthreads();
#pragma unroll
        for (int kk = 0; kk < 8; kk++) {
            float b0 = Bs[(k0 + kk) * 96 + tx];
            float b1 = Bs[(k0 + kk) * 96 + 32 + tx];
            float b2 = Bs[(k0 + kk) * 96 + 64 + tx];
            const float4* ap = (const float4*)(AsT + kk * 128 + ty * 16);
            float4 a0 = ap[0], a1 = ap[1], a2 = ap[2], a3 = ap[3];
            float av[16] = {a0.x,a0.y,a0.z,a0.w, a1.x,a1.y,a1.z,a1.w,
                            a2.x,a2.y,a2.z,a2.w, a3.x,a3.y,a3.z,a3.w};
#pragma unroll
            for (int r = 0; r < 16; r++) {
                acc0[r] = fmaf(av[r], b0, acc0[r]);
                acc1[r] = fmaf(av[r], b1, acc1[r]);
                acc2[r] = fmaf(av[r], b2, acc2[r]);
            }
        }
    }
#pragma unroll
    for (int r = 0; r < 16; r++) {
        int gr = rowBase + ty * 16 + r;
        if (gr < NN) {
            float di = dinv[gr];
            ushort* o = xw16 + (long long)gr * 128;   // 256B row
            uint w0 = (uint)f2bf(acc0[r] * di) | ((uint)f2bf(acc1[r] * di) << 16);
            uint w1 = (uint)f2bf(acc2[r] * di);
            uint2 pk; pk.x = w0; pk.y = w1;
            *(uint2*)(o + 4 * tx) = pk;               // 8B aligned, coalesced
        }
    }
}

// ---------------- fused gather-aggregate + GRU gates + head ----------------
// 32-lane group per node; 16 nodes / 512-thread block; NN = 6250*16 exactly.
// xw16 rows pre-scaled by dinv[row]:  agg = dinv[col]*(sum w_e*xw'[row_e] + xw'[col])
// One 8B load per lane per edge (interleaved layout).
// BARRIERS KEPT (register-pressure fences): removing them -> VGPR 80,
// occupancy 22% (rounds 3/4). With barriers, VGPR stays at 32 and occupancy
// is LDS-limited at 4 blocks/CU. Unroll-8 first tier (round 6: +3%).
__global__ __launch_bounds__(512) void agg_gate_kernel(
        const uint* __restrict__ erecF, const int* __restrict__ estart, const int* __restrict__ cnt,
        const ushort* __restrict__ xw16, const float* __restrict__ dinv,
        const float* __restrict__ hprev,
        const float* __restrict__ bcz, const float* __restrict__ bcr, const float* __restrict__ bch,
        const float* __restrict__ Wlz, const float* __restrict__ blz,
        const float* __restrict__ Wlr, const float* __restrict__ blr,
        const float* __restrict__ Wlh, const float* __restrict__ blh,
        const float* __restrict__ Whead, const float* __restrict__ bhead,
        float* __restrict__ y, float* __restrict__ hnew) {
    __shared__ float WzT[64 * 32], WrT[64 * 32], WhT[64 * 32];  // WT[k*32+j] = Wl[j*64+k]
    __shared__ float czs[16][32], crs[16][32], chs[16][32], hps[16][32], rhs[16][32];
    __shared__ uint rwsh[16][32];   // staged records per group
    int tid = threadIdx.x;
    for (int e2 = tid; e2 < 2048; e2 += 512) {
        int jj = e2 >> 6, k = e2 & 63;
        WzT[k * 32 + jj] = Wlz[e2];
        WrT[k * 32 + jj] = Wlr[e2];
        WhT[k * 32 + jj] = Wlh[e2];
    }
    int s = tid >> 5, j = tid & 31;
    int i = blockIdx.x * 16 + s;
    int beg = estart[i], c = cnt[i], end = beg + c;

    const char* xwb = (const char*)xw16;
    uint jo8 = 8u * (uint)j;            // byte offset of feature j's 8B cell

    float cz = 0.f, cr = 0.f, ch = 0.f;
    int e = beg + j;
    uint vcur = (e < end) ? __builtin_nontemporal_load(erecF + e) : 0u;   // batch 0
    __syncthreads();   // WT staging complete

#define REC(vv, dd)                                                        \
    {                                                                      \
        float w_ = __uint_as_float(((vv) >> 17) << 16);                    \
        cz = fmaf(w_, __uint_as_float((dd).x << 16), cz);                  \
        cr = fmaf(w_, __uint_as_float((dd).x & 0xFFFF0000u), cr);          \
        ch = fmaf(w_, __uint_as_float((dd).y << 16), ch);                  \
    }

    for (int base = beg; base < end; base += 32) {
        rwsh[s][j] = vcur;                      // in-order DS within wave: safe
        int en = base + 32 + j;
        uint vnext = (en < end) ? __builtin_nontemporal_load(erecF + en) : 0u;  // prefetch next batch
        int mm = end - base; if (mm > 32) mm = 32;
        int t = 0;
        for (; t + 8 <= mm; t += 8) {           // 8 x 8B gathers in flight per group
            uint v0 = rwsh[s][t + 0], v1 = rwsh[s][t + 1], v2 = rwsh[s][t + 2], v3 = rwsh[s][t + 3];
            uint v4 = rwsh[s][t + 4], v5 = rwsh[s][t + 5], v6 = rwsh[s][t + 6], v7 = rwsh[s][t + 7];
            uint b0 = (v0 & 0x1FFFFu) * 256u, b1 = (v1 & 0x1FFFFu) * 256u;
            uint b2 = (v2 & 0x1FFFFu) * 256u, b3 = (v3 & 0x1FFFFu) * 256u;
            uint b4 = (v4 & 0x1FFFFu) * 256u, b5 = (v5 & 0x1FFFFu) * 256u;
            uint b6 = (v6 & 0x1FFFFu) * 256u, b7 = (v7 & 0x1FFFFu) * 256u;
            uint2 d0 = *(const uint2*)(xwb + b0 + jo8);
            uint2 d1 = *(const uint2*)(xwb + b1 + jo8);
            uint2 d2 = *(const uint2*)(xwb + b2 + jo8);
            uint2 d3 = *(const uint2*)(xwb + b3 + jo8);
            uint2 d4 = *(const uint2*)(xwb + b4 + jo8);
            uint2 d5 = *(const uint2*)(xwb + b5 + jo8);
            uint2 d6 = *(const uint2*)(xwb + b6 + jo8);
            uint2 d7 = *(const uint2*)(xwb + b7 + jo8);
            REC(v0, d0) REC(v1, d1) REC(v2, d2) REC(v3, d3)
            REC(v4, d4) REC(v5, d5) REC(v6, d6) REC(v7, d7)
        }
        for (; t + 4 <= mm; t += 4) {
            uint v0 = rwsh[s][t + 0], v1 = rwsh[s][t + 1], v2 = rwsh[s][t + 2], v3 = rwsh[s][t + 3];
            uint b0 = (v0 & 0x1FFFFu) * 256u, b1 = (v1 & 0x1FFFFu) * 256u;
            uint b2 = (v2 & 0x1FFFFu) * 256u, b3 = (v3 & 0x1FFFFu) * 256u;
            uint2 d0 = *(const uint2*)(xwb + b0 + jo8);
            uint2 d1 = *(const uint2*)(xwb + b1 + jo8);
            uint2 d2 = *(const uint2*)(xwb + b2 + jo8);
            uint2 d3 = *(const uint2*)(xwb + b3 + jo8);
            REC(v0, d0) REC(v1, d1) REC(v2, d2) REC(v3, d3)
        }
        for (; t < mm; t++) {
            uint v0 = rwsh[s][t];
            uint b0 = (v0 & 0x1FFFFu) * 256u;
            uint2 d0 = *(const uint2*)(xwb + b0 + jo8);
            REC(v0, d0)
        }
        vcur = vnext;
    }
#undef REC

    // self-loop + dinv[col] + bias:  c* = di*(sum + xw'[i]) + bc
    float di = dinv[i];
    uint2 dself = *(const uint2*)(xwb + (uint)i * 256u + jo8);
    czs[s][j] = fmaf(di, cz + __uint_as_float(dself.x << 16), bcz[j]);
    crs[s][j] = fmaf(di, cr + __uint_as_float(dself.x & 0xFFFF0000u), bcr[j]);
    chs[s][j] = fmaf(di, ch + __uint_as_float(dself.y << 16), bch[j]);
    float hp = hprev[(long long)i * HD + j];
    hps[s][j] = hp;
    __syncthreads();   // register-pressure fence + cross-group visibility

    float az = blz[j], arv = blr[j];
#pragma unroll
    for (int k = 0; k < 32; k++) {
        az  = fmaf(WzT[k * 32 + j], czs[s][k], az);
        arv = fmaf(WrT[k * 32 + j], crs[s][k], arv);
    }
#pragma unroll
    for (int k = 0; k < 32; k++) {
        float v = hps[s][k];
        az  = fmaf(WzT[(k + 32) * 32 + j], v, az);
        arv = fmaf(WrT[(k + 32) * 32 + j], v, arv);
    }
    float Z = 1.f / (1.f + __expf(-az));
    float R = 1.f / (1.f + __expf(-arv));
    rhs[s][j] = hp * R;
    __syncthreads();   // register-pressure fence

    float ah = blh[j];
#pragma unroll
    for (int k = 0; k < 32; k++) ah = fmaf(WhT[k * 32 + j], chs[s][k], ah);
#pragma unroll
    for (int k = 0; k < 32; k++) ah = fmaf(WhT[(k + 32) * 32 + j], rhs[s][k], ah);
    float Ht = tanhf(ah);
    float hn = Z * hp + (1.f - Z) * Ht;
    float yv = fmaxf(hn, 0.f) * Whead[j];
#pragma unroll
    for (int m = 16; m; m >>= 1) yv += __shfl_xor(yv, m, 32);
    hnew[(long long)i * HD + j] = hn;
    if (j == 0) y[i] = yv + bhead[0];
}

extern "C" void kernel_launch(void* const* d_in, const int* in_sizes, int n_in,
                              void* d_out, int out_size, void* d_ws, size_t ws_size,
                              hipStream_t stream) {
    const float* x     = (const float*)d_in[0];
    const int*   ei    = (const int*)d_in[1];
    const float* wt    = (const float*)d_in[2];
    const float* hprev = (const float*)d_in[3];
    const float* Wcz = (const float*)d_in[4],  *bcz = (const float*)d_in[5];
    const float* Wlz = (const float*)d_in[6],  *blz = (const float*)d_in[7];
    const float* Wcr = (const float*)d_in[8],  *bcr = (const float*)d_in[9];
    const float* Wlr = (const float*)d_in[10], *blr = (const float*)d_in[11];
    const float* Wch = (const float*)d_in[12], *bch = (const float*)d_in[13];
    const float* Wlh = (const float*)d_in[14], *blh = (const float*)d_in[15];
    const float* Whead = (const float*)d_in[16], *bhead = (const float*)d_in[17];

    float* out_y = (float*)d_out;            // [N]
    float* out_h = (float*)d_out + NN;       // [N,32]

    float* ws = (float*)d_ws;
    float* dinv      = ws;                                   // NN f32
    int*   estart    = (int*)(ws + NN);                      // NN
    int*   cnt       = (int*)(ws + 2LL * NN);                // NN
    int*   gcur      = (int*)(ws + 3LL * NN);                // NBUK cursors, 64B-padded (6400 ints)
    uint2* erec2     = (uint2*)(ws + 3LL * NN + 6400);       // NBUK*CAP uint2 (32 MB, 8B-aligned)
    ushort* xw16     = (ushort*)erec2;                       // ALIAS: NN*256B (25.6MB) <= slab (32MB)
    uint*  erecF     = (uint*)(ws + 3LL * NN + 6400 + 2LL * NBUK * CAP);  // NBUK*CAP uint (16 MB)

    zero_gcur<<<1, 512, 0, stream>>>(gcur);
    sortC_fused<<<NBLK, 512, 0, stream>>>(ei, wt, gcur, erec2);
    passB_fine<<<NBUK, 512, 0, stream>>>(erec2, gcur, erecF, estart, cnt, dinv);
    gemm_xw_kernel<<<(NN + 127) / 128, 256, 0, stream>>>(x, Wcz, Wcr, Wch, dinv, xw16);
    agg_gate_kernel<<<NN / 16, 512, 0, stream>>>(
        erecF, estart, cnt, xw16, dinv, hprev, bcz, bcr, bch,
        Wlz, blz, Wlr, blr, Wlh, blh, Whead, bhead, out_y, out_h);
}